// Round 9
// baseline (219.993 us; speedup 1.0000x reference)
//
#include <hip/hip_runtime.h>

// Problem constants
#define BSEQ 64
#define LSEQ 512
#define CCH  1024
#define NT   7            // NUM_TAGS
#define NC   5            // real classes (labels are always 0..4)
#define NTOK (BSEQ*LSEQ)  // 32768
#define START_TAG 5
#define STOP_TAG  6
#define NEGV (-10000.0f)
#define GRID_LOGITS 1024  // k_logits assumes exactly this grid (2 iters/wave, 4 rows/iter)

typedef float vfloat4 __attribute__((ext_vector_type(4)));

// ---------------- DPP wave64 sum (result lands in lane 63) ----------------
template<int CTRL, int RMASK, int BMASK>
__device__ __forceinline__ float dpp_add(float x) {
    int y = __builtin_amdgcn_update_dpp(0, __float_as_int(x), CTRL, RMASK, BMASK, true);
    return x + __int_as_float(y);
}
__device__ __forceinline__ float wave_sum(float x) {
    x = dpp_add<0x111, 0xF, 0xF>(x);  // row_shr:1
    x = dpp_add<0x112, 0xF, 0xF>(x);  // row_shr:2
    x = dpp_add<0x114, 0xF, 0xF>(x);  // row_shr:4
    x = dpp_add<0x118, 0xF, 0xF>(x);  // row_shr:8  -> lane15 of each row16 has row sum
    x = dpp_add<0x142, 0xA, 0xF>(x);  // row_bcast:15 into rows 1,3
    x = dpp_add<0x143, 0xC, 0xF>(x);  // row_bcast:31 into rows 2,3 -> lane63 = total
    return x;
}

// 5-way log-sum-exp helper
__device__ __forceinline__ float lse5(const float v0, const float v1, const float v2,
                                      const float v3, const float v4) {
    float m = fmaxf(fmaxf(fmaxf(v0, v1), fmaxf(v2, v3)), v4);
    float s = __expf(v0 - m) + __expf(v1 - m) + __expf(v2 - m)
            + __expf(v3 - m) + __expf(v4 - m);
    return m + __logf(s);
}

// ---------------- Kernel 1: logits (X @ W^T + b), labels copy, score zero ----------------
// R8 post-mortem: LDS/VALU/prefetch/occupancy all ruled out (3 neutral rounds
// at ~59 us / 2.3 TB/s). Remaining suspects: (1) nt streaming-load path is
// rate-capped; (2) per-row-group ds_read->fma waitcnt chains serialize waves.
// This round kills both: W hoisted to 112 VGPRs per lane (lane's W columns are
// fixed by its load offsets, identical for every row -> read LDS once, loop
// has ZERO lgkmcnt), and plain global loads (no nt). VGPR ~220 -> 8 waves/CU;
// occupancy-insensitivity measured (R2 vs R4), so the drop is safe.
// NOTE: plain __launch_bounds__(256) — R3 showed (256,4) clamps to 64 VGPR
// and spills 88 MB.
__global__ __launch_bounds__(256)
void k_logits(const float* __restrict__ X, const float* __restrict__ W,
              const float* __restrict__ bvec, const int* __restrict__ lab,
              float* __restrict__ out)
{
    __shared__ float Wl[NT][CCH];   // 28 KB, read once per lane after staging
    __shared__ float bl[NT];
    {
        const vfloat4* W4  = (const vfloat4*)W;
        vfloat4*       Wl4 = (vfloat4*)(&Wl[0][0]);
        for (int i = threadIdx.x; i < NT*CCH/4; i += 256) Wl4[i] = W4[i];
        if (threadIdx.x < NT) bl[threadIdx.x] = bvec[threadIdx.x];
    }
    __syncthreads();

    const int lane = threadIdx.x & 63;
    const int wid  = (blockIdx.x * 256 + threadIdx.x) >> 6;
    const int nw   = (GRID_LOGITS * 256) >> 6;      // 4096 waves
    float* outP = out + 1 + NTOK;

    // hoist W into registers: lane's columns are (k*64+lane)*4, k=0..3 —
    // the same for every row this lane ever processes.
    vfloat4 wreg[4][NT];   // 112 VGPRs
    #pragma unroll
    for (int k = 0; k < 4; k++) {
        const int cb = (k*64 + lane) * 4;
        #pragma unroll
        for (int t = 0; t < NT; t++)
            wreg[k][t] = *(const vfloat4*)(&Wl[t][cb]);
    }

    #pragma unroll
    for (int it = 0; it < 2; ++it) {
        const size_t base = (size_t)(wid + it * nw) * 4;

        // issue all 16 row-loads up front (16 KB in flight per wave)
        vfloat4 xv[4][4];   // [row][k]
        #pragma unroll
        for (int r = 0; r < 4; r++) {
            const vfloat4* xr = (const vfloat4*)(X + (base + r) * CCH);
            #pragma unroll
            for (int k = 0; k < 4; k++)
                xv[r][k] = xr[k*64 + lane];
        }
        __builtin_amdgcn_sched_barrier(0);   // keep the load block intact

        float acc[4][NT];
        #pragma unroll
        for (int r = 0; r < 4; r++)
            #pragma unroll
            for (int t = 0; t < NT; t++) acc[r][t] = 0.0f;

        #pragma unroll
        for (int k = 0; k < 4; k++) {
            #pragma unroll
            for (int t = 0; t < NT; t++) {
                const vfloat4 wv = wreg[k][t];   // registers — no LDS in loop
                #pragma unroll
                for (int r = 0; r < 4; r++) {
                    acc[r][t] = fmaf(xv[r][k].x, wv.x,
                                fmaf(xv[r][k].y, wv.y,
                                fmaf(xv[r][k].z, wv.z,
                                fmaf(xv[r][k].w, wv.w, acc[r][t]))));
                }
            }
        }

        #pragma unroll
        for (int r = 0; r < 4; r++) {
            #pragma unroll
            for (int t = 0; t < NT; t++) {
                float s = wave_sum(acc[r][t]);
                if (lane == 63) outP[(base + r) * NT + t] = s + bl[t];
            }
        }
    }

    // labels as float + zero the score slot
    for (int i = blockIdx.x * 256 + threadIdx.x; i < NTOK; i += GRID_LOGITS * 256)
        out[1 + i] = (float)lab[i];
    if (blockIdx.x == 0 && threadIdx.x == 0) out[0] = 0.0f;
}

// ---------------- Kernel 2: CRF NLL, 5-class log-semiring chunked scan ----------------
// transitions[START,:]=NEG and [:,STOP]=NEG make the recurrence exactly 5x5 in
// fp32 (START enters only via step-0 injection u[k]=T[k,START]+e0[k]; STOP only
// at the final fold; all other START/STOP terms are exp(-10000-m) == 0.0f).
// Chunk 0 covers steps 1..7, chunks 1..63 cover 8 steps. 64 blocks x 320 thr
// (= 64 chunks x 5 basis). Tree-combine 64 5x5 matrices, fold u and T[STOP,:].
__global__ __launch_bounds__(320)
void k_crf(const float* __restrict__ dout_ro, const int* __restrict__ lab,
           const float* __restrict__ trans, float* __restrict__ score)
{
    __shared__ float E[LSEQ*NT];   // 3584 floats; reused as matrix buffer A after recurrence
    __shared__ float M2[32*25];    // ping-pong buffer B
    __shared__ float T[49];
    __shared__ float u_sh[NC];     // fv after step 0 (START injection)
    __shared__ float gred[5];

    const int b   = blockIdx.x;
    const int tid = threadIdx.x;
    const float* feats = dout_ro + 1 + NTOK + (size_t)b * (LSEQ*NT);

    for (int i = tid; i < LSEQ*NT; i += 320) E[i] = feats[i];
    if (tid < 49) T[tid] = trans[tid];
    __syncthreads();

    if (tid < NC) u_sh[tid] = T[tid*NT + START_TAG] + E[tid];   // e0[k] before E is overwritten

    // ---- gold score (parallel over tokens) ----
    float g = 0.0f;
    for (int l = tid; l < LSEQ; l += 320) {
        const int t  = lab[b*LSEQ + l];
        const int tp = (l == 0) ? START_TAG : lab[b*LSEQ + l - 1];
        g += E[l*NT + t] + T[t*NT + tp];
    }
    if (tid == 0) g += T[STOP_TAG*NT + lab[b*LSEQ + LSEQ - 1]];
    {
        float gs = wave_sum(g);
        if ((tid & 63) == 63) gred[tid >> 6] = gs;
    }

    // ---- chunk basis recurrences (5x5, all in registers) ----
    float TR[NC*NC];
    #pragma unroll
    for (int j = 0; j < NC; j++)
        #pragma unroll
        for (int k = 0; k < NC; k++) TR[j*NC + k] = T[j*NT + k];

    const int chunk = tid / NC;
    const int basis = tid - chunk * NC;
    float fv[NC];
    #pragma unroll
    for (int j = 0; j < NC; j++) fv[j] = (j == basis) ? 0.0f : NEGV;

    const int l0    = (chunk == 0) ? 1 : chunk * 8;
    const int steps = (chunk == 0) ? 7 : 8;
    for (int s = 0; s < steps; s++) {
        const int l = l0 + s;
        float fn[NC];
        #pragma unroll
        for (int j = 0; j < NC; j++) {
            fn[j] = lse5(fv[0] + TR[j*NC+0], fv[1] + TR[j*NC+1], fv[2] + TR[j*NC+2],
                         fv[3] + TR[j*NC+3], fv[4] + TR[j*NC+4]) + E[l*NT + j];
        }
        #pragma unroll
        for (int j = 0; j < NC; j++) fv[j] = fn[j];
    }
    __syncthreads();   // all E reads done; safe to overwrite with matrices
    #pragma unroll
    for (int j = 0; j < NC; j++) E[chunk*25 + basis*NC + j] = fv[j];

    // ---- tree combine: C[i][j] = lse_k(A[i][k] + B[k][j]), chronological L->R ----
    // (no LDS-pointer arrays: addrspacecast static-init is rejected on gfx950)
    int n = 64, cur = 0;
    while (n > 1) {
        __syncthreads();
        const float* in = (cur == 0) ? (const float*)E : (const float*)M2;
        float*       ob = (cur == 0) ? M2 : E;
        const int half = n >> 1;
        for (int e2 = tid; e2 < half*25; e2 += 320) {
            const int p = e2 / 25, r = e2 - p*25;
            const int i = r / NC, j = r - (r/NC)*NC;
            const float* A  = in + (2*p)*25 + i*NC;
            const float* Bm = in + (2*p + 1)*25 + j;
            ob[p*25 + r] = lse5(A[0] + Bm[0], A[1] + Bm[NC], A[2] + Bm[2*NC],
                                A[3] + Bm[3*NC], A[4] + Bm[4*NC]);
        }
        cur ^= 1; n = half;
    }
    __syncthreads();

    if (tid == 0) {
        float gg = gred[0] + gred[1] + gred[2] + gred[3] + gred[4];
        const float* M = (cur == 0) ? (const float*)E : (const float*)M2;  // final 5x5
        float v[NC];
        #pragma unroll
        for (int j = 0; j < NC; j++)
            v[j] = lse5(u_sh[0] + M[0*NC+j], u_sh[1] + M[1*NC+j], u_sh[2] + M[2*NC+j],
                        u_sh[3] + M[3*NC+j], u_sh[4] + M[4*NC+j]);
        float fwd = lse5(v[0] + T[STOP_TAG*NT+0], v[1] + T[STOP_TAG*NT+1],
                         v[2] + T[STOP_TAG*NT+2], v[3] + T[STOP_TAG*NT+3],
                         v[4] + T[STOP_TAG*NT+4]);
        atomicAdd(score, fwd - gg);
    }
}

extern "C" void kernel_launch(void* const* d_in, const int* in_sizes, int n_in,
                              void* d_out, int out_size, void* d_ws, size_t ws_size,
                              hipStream_t stream) {
    const float* X     = (const float*)d_in[0];   // fuse_embeddings [32768,1024]
    const int*   lab   = (const int*)  d_in[1];   // label_class [32768]
    const float* W     = (const float*)d_in[2];   // [7,1024]
    const float* bvec  = (const float*)d_in[3];   // [7]
    const float* trans = (const float*)d_in[4];   // [7,7]
    float* out = (float*)d_out;

    k_logits<<<GRID_LOGITS, 256, 0, stream>>>(X, W, bvec, lab, out);
    k_crf<<<BSEQ, 320, 0, stream>>>(out, lab, trans, out);
}

// Round 10
// 210.152 us; speedup vs baseline: 1.0468x; 1.0468x over previous
//
#include <hip/hip_runtime.h>

// Problem constants
#define BSEQ 64
#define LSEQ 512
#define CCH  1024
#define NT   7            // NUM_TAGS
#define NC   5            // real classes (labels are always 0..4)
#define NTOK (BSEQ*LSEQ)  // 32768
#define START_TAG 5
#define STOP_TAG  6
#define NEGV (-10000.0f)
#define GRID_LOGITS 1024  // k_logits assumes exactly this grid (2 iters/wave, 4 rows/iter)

typedef float vfloat4 __attribute__((ext_vector_type(4)));

// ---------------- DPP wave64 sum (result lands in lane 63) ----------------
template<int CTRL, int RMASK, int BMASK>
__device__ __forceinline__ float dpp_add(float x) {
    int y = __builtin_amdgcn_update_dpp(0, __float_as_int(x), CTRL, RMASK, BMASK, true);
    return x + __int_as_float(y);
}
__device__ __forceinline__ float wave_sum(float x) {
    x = dpp_add<0x111, 0xF, 0xF>(x);  // row_shr:1
    x = dpp_add<0x112, 0xF, 0xF>(x);  // row_shr:2
    x = dpp_add<0x114, 0xF, 0xF>(x);  // row_shr:4
    x = dpp_add<0x118, 0xF, 0xF>(x);  // row_shr:8  -> lane15 of each row16 has row sum
    x = dpp_add<0x142, 0xA, 0xF>(x);  // row_bcast:15 into rows 1,3
    x = dpp_add<0x143, 0xC, 0xF>(x);  // row_bcast:31 into rows 2,3 -> lane63 = total
    return x;
}

// 5-way log-sum-exp helper
__device__ __forceinline__ float lse5(const float v0, const float v1, const float v2,
                                      const float v3, const float v4) {
    float m = fmaxf(fmaxf(fmaxf(v0, v1), fmaxf(v2, v3)), v4);
    float s = __expf(v0 - m) + __expf(v1 - m) + __expf(v2 - m)
            + __expf(v3 - m) + __expf(v4 - m);
    return m + __logf(s);
}

// ---------------- Kernel 1: logits (X @ W^T + b), labels copy, score zero ----------------
// R9 synthesis: nt = -10us, ALL structural reorderings = 0. R3's spilled
// variant moved MORE total bytes/s (2.8 vs 2.3 TB/s) -> issue-pattern cap,
// not BW. Theory: vmcnt is IN-ORDER and counts stores; the 28 scalar
// global stores at each iteration's end sit ahead of the next load-use
// s_waitcnt in the queue, so every wave stalls behind its own scattered
// HBM writebacks. Fix: all 32 loads issued up-front (iter0 compute waits
// partial vmcnt(16)); results staged in LDS; ONE coalesced store sweep at
// kernel end (2 x 448B contiguous per block). No global store ever precedes
// a load-use wait. VGPR ~185 -> 8 waves/CU (occupancy-insensitive, R2=R4).
// NOTE: plain __launch_bounds__(256) — R3 showed (256,4) clamps to 64 VGPR
// and spills 88 MB.
__global__ __launch_bounds__(256)
void k_logits(const float* __restrict__ X, const float* __restrict__ W,
              const float* __restrict__ bvec, const int* __restrict__ lab,
              float* __restrict__ out)
{
    __shared__ float Wl[NT][CCH];   // 28 KB
    __shared__ float bl[NT];
    __shared__ float res[2][112];   // [iter][(wave*4+r)*7+t] staged results
    {
        const vfloat4* W4  = (const vfloat4*)W;
        vfloat4*       Wl4 = (vfloat4*)(&Wl[0][0]);
        for (int i = threadIdx.x; i < NT*CCH/4; i += 256) Wl4[i] = W4[i];
        if (threadIdx.x < NT) bl[threadIdx.x] = bvec[threadIdx.x];
    }
    __syncthreads();

    const int lane = threadIdx.x & 63;
    const int w    = threadIdx.x >> 6;              // wave in block (0..3)
    const int wid  = (blockIdx.x * 256 + threadIdx.x) >> 6;
    const int nw   = (GRID_LOGITS * 256) >> 6;      // 4096 waves
    float* outP = out + 1 + NTOK;

    // issue ALL 32 row-loads up-front: iter0 rows then iter1 rows.
    // iter0 compute will wait vmcnt(16) (iter1 still in flight).
    vfloat4 xv[2][4][4];   // [iter][row][k] = 128 VGPRs
    #pragma unroll
    for (int it = 0; it < 2; ++it) {
        const size_t base = (size_t)(wid + it * nw) * 4;
        #pragma unroll
        for (int r = 0; r < 4; r++) {
            const vfloat4* xr = (const vfloat4*)(X + (base + r) * CCH);
            #pragma unroll
            for (int k = 0; k < 4; k++)
                xv[it][r][k] = __builtin_nontemporal_load(&xr[k*64 + lane]);
        }
    }
    __builtin_amdgcn_sched_barrier(0);   // keep the 32-load block intact

    #pragma unroll
    for (int it = 0; it < 2; ++it) {
        float acc[4][NT];
        #pragma unroll
        for (int r = 0; r < 4; r++)
            #pragma unroll
            for (int t = 0; t < NT; t++) acc[r][t] = 0.0f;

        #pragma unroll
        for (int k = 0; k < 4; k++) {
            const int cb = (k*64 + lane) * 4;
            #pragma unroll
            for (int t = 0; t < NT; t++) {
                const vfloat4 wv = *(const vfloat4*)(&Wl[t][cb]);   // 1 b128 serves 4 rows
                #pragma unroll
                for (int r = 0; r < 4; r++) {
                    acc[r][t] = fmaf(xv[it][r][k].x, wv.x,
                                fmaf(xv[it][r][k].y, wv.y,
                                fmaf(xv[it][r][k].z, wv.z,
                                fmaf(xv[it][r][k].w, wv.w, acc[r][t]))));
                }
            }
        }

        // reduce and stage to LDS (lgkmcnt path — stays out of the vmem queue)
        #pragma unroll
        for (int r = 0; r < 4; r++) {
            #pragma unroll
            for (int t = 0; t < NT; t++) {
                float s = wave_sum(acc[r][t]);
                if (lane == 63) res[it][(w*4 + r)*NT + t] = s + bl[t];
            }
        }
    }
    __syncthreads();

    // one coalesced store sweep: two contiguous 448-B segments per block.
    // iter0 rows b*16..b*16+15 -> outP[b*112 ..]; iter1 rows 16384+b*16..
    {
        const int tid = threadIdx.x;
        if (tid < 112)
            outP[(size_t)blockIdx.x * 112 + tid] = res[0][tid];
        else if (tid >= 128 && tid < 240)
            outP[(size_t)16384 * NT + (size_t)blockIdx.x * 112 + (tid - 128)] = res[1][tid - 128];
    }

    // labels as float + zero the score slot (after all result stores)
    for (int i = blockIdx.x * 256 + threadIdx.x; i < NTOK; i += GRID_LOGITS * 256)
        out[1 + i] = (float)lab[i];
    if (blockIdx.x == 0 && threadIdx.x == 0) out[0] = 0.0f;
}

// ---------------- Kernel 2: CRF NLL, 5-class log-semiring chunked scan ----------------
// transitions[START,:]=NEG and [:,STOP]=NEG make the recurrence exactly 5x5 in
// fp32 (START enters only via step-0 injection u[k]=T[k,START]+e0[k]; STOP only
// at the final fold; all other START/STOP terms are exp(-10000-m) == 0.0f).
// Chunk 0 covers steps 1..7, chunks 1..63 cover 8 steps. 64 blocks x 320 thr
// (= 64 chunks x 5 basis). Tree-combine 64 5x5 matrices, fold u and T[STOP,:].
__global__ __launch_bounds__(320)
void k_crf(const float* __restrict__ dout_ro, const int* __restrict__ lab,
           const float* __restrict__ trans, float* __restrict__ score)
{
    __shared__ float E[LSEQ*NT];   // 3584 floats; reused as matrix buffer A after recurrence
    __shared__ float M2[32*25];    // ping-pong buffer B
    __shared__ float T[49];
    __shared__ float u_sh[NC];     // fv after step 0 (START injection)
    __shared__ float gred[5];

    const int b   = blockIdx.x;
    const int tid = threadIdx.x;
    const float* feats = dout_ro + 1 + NTOK + (size_t)b * (LSEQ*NT);

    for (int i = tid; i < LSEQ*NT; i += 320) E[i] = feats[i];
    if (tid < 49) T[tid] = trans[tid];
    __syncthreads();

    if (tid < NC) u_sh[tid] = T[tid*NT + START_TAG] + E[tid];   // e0[k] before E is overwritten

    // ---- gold score (parallel over tokens) ----
    float g = 0.0f;
    for (int l = tid; l < LSEQ; l += 320) {
        const int t  = lab[b*LSEQ + l];
        const int tp = (l == 0) ? START_TAG : lab[b*LSEQ + l - 1];
        g += E[l*NT + t] + T[t*NT + tp];
    }
    if (tid == 0) g += T[STOP_TAG*NT + lab[b*LSEQ + LSEQ - 1]];
    {
        float gs = wave_sum(g);
        if ((tid & 63) == 63) gred[tid >> 6] = gs;
    }

    // ---- chunk basis recurrences (5x5, all in registers) ----
    float TR[NC*NC];
    #pragma unroll
    for (int j = 0; j < NC; j++)
        #pragma unroll
        for (int k = 0; k < NC; k++) TR[j*NC + k] = T[j*NT + k];

    const int chunk = tid / NC;
    const int basis = tid - chunk * NC;
    float fv[NC];
    #pragma unroll
    for (int j = 0; j < NC; j++) fv[j] = (j == basis) ? 0.0f : NEGV;

    const int l0    = (chunk == 0) ? 1 : chunk * 8;
    const int steps = (chunk == 0) ? 7 : 8;
    for (int s = 0; s < steps; s++) {
        const int l = l0 + s;
        float fn[NC];
        #pragma unroll
        for (int j = 0; j < NC; j++) {
            fn[j] = lse5(fv[0] + TR[j*NC+0], fv[1] + TR[j*NC+1], fv[2] + TR[j*NC+2],
                         fv[3] + TR[j*NC+3], fv[4] + TR[j*NC+4]) + E[l*NT + j];
        }
        #pragma unroll
        for (int j = 0; j < NC; j++) fv[j] = fn[j];
    }
    __syncthreads();   // all E reads done; safe to overwrite with matrices
    #pragma unroll
    for (int j = 0; j < NC; j++) E[chunk*25 + basis*NC + j] = fv[j];

    // ---- tree combine: C[i][j] = lse_k(A[i][k] + B[k][j]), chronological L->R ----
    // (no LDS-pointer arrays: addrspacecast static-init is rejected on gfx950)
    int n = 64, cur = 0;
    while (n > 1) {
        __syncthreads();
        const float* in = (cur == 0) ? (const float*)E : (const float*)M2;
        float*       ob = (cur == 0) ? M2 : E;
        const int half = n >> 1;
        for (int e2 = tid; e2 < half*25; e2 += 320) {
            const int p = e2 / 25, r = e2 - p*25;
            const int i = r / NC, j = r - (r/NC)*NC;
            const float* A  = in + (2*p)*25 + i*NC;
            const float* Bm = in + (2*p + 1)*25 + j;
            ob[p*25 + r] = lse5(A[0] + Bm[0], A[1] + Bm[NC], A[2] + Bm[2*NC],
                                A[3] + Bm[3*NC], A[4] + Bm[4*NC]);
        }
        cur ^= 1; n = half;
    }
    __syncthreads();

    if (tid == 0) {
        float gg = gred[0] + gred[1] + gred[2] + gred[3] + gred[4];
        const float* M = (cur == 0) ? (const float*)E : (const float*)M2;  // final 5x5
        float v[NC];
        #pragma unroll
        for (int j = 0; j < NC; j++)
            v[j] = lse5(u_sh[0] + M[0*NC+j], u_sh[1] + M[1*NC+j], u_sh[2] + M[2*NC+j],
                        u_sh[3] + M[3*NC+j], u_sh[4] + M[4*NC+j]);
        float fwd = lse5(v[0] + T[STOP_TAG*NT+0], v[1] + T[STOP_TAG*NT+1],
                         v[2] + T[STOP_TAG*NT+2], v[3] + T[STOP_TAG*NT+3],
                         v[4] + T[STOP_TAG*NT+4]);
        atomicAdd(score, fwd - gg);
    }
}

extern "C" void kernel_launch(void* const* d_in, const int* in_sizes, int n_in,
                              void* d_out, int out_size, void* d_ws, size_t ws_size,
                              hipStream_t stream) {
    const float* X     = (const float*)d_in[0];   // fuse_embeddings [32768,1024]
    const int*   lab   = (const int*)  d_in[1];   // label_class [32768]
    const float* W     = (const float*)d_in[2];   // [7,1024]
    const float* bvec  = (const float*)d_in[3];   // [7]
    const float* trans = (const float*)d_in[4];   // [7,7]
    float* out = (float*)d_out;

    k_logits<<<GRID_LOGITS, 256, 0, stream>>>(X, W, bvec, lab, out);
    k_crf<<<BSEQ, 320, 0, stream>>>(out, lab, trans, out);
}